// Round 5
// baseline (450.656 us; speedup 1.0000x reference)
//
#include <hip/hip_runtime.h>

#define LEAKY(v) ((v) > 0.0f ? (v) : 0.01f * (v))
#define SCAN_B 256

// ---------------------------------------------------------------------------
// int64-vs-int32 edge_index detection (little-endian, values < 2^31: odd
// 32-bit words of an int64 array are all 0; random int32 src values are not).
// ---------------------------------------------------------------------------
__device__ __forceinline__ int detect_is64(const unsigned* ei, int E) {
    __shared__ int is64_s;
    if (threadIdx.x == 0) {
        int z = 1;
        int limit = 2 * E < 128 ? 2 * E : 128;
        for (int i = 1; i < limit; i += 2)
            if (ei[i] != 0u) { z = 0; break; }
        is64_s = z;
    }
    __syncthreads();
    return is64_s;
}

// degree histogram straight off edge_index (dst half only)
__global__ void hist_kernel(const unsigned* __restrict__ ei, int* __restrict__ deg, int E) {
    int is64 = detect_is64(ei, E);
    int e = blockIdx.x * blockDim.x + threadIdx.x;
    if (e < E) {
        int d = is64 ? (int)ei[2 * (size_t)E + 2 * (size_t)e] : (int)ei[(size_t)E + e];
        atomicAdd(&deg[d], 1);
    }
}

__global__ void dinv_kernel(const int* __restrict__ deg, float* __restrict__ dinv, int N) {
    int i = blockIdx.x * blockDim.x + threadIdx.x;
    if (i < N) dinv[i] = rsqrtf((float)deg[i] + 1.0f);
}

// ---- two-level exclusive scan of deg -> row_ofs (CSR), cur = copy ----------
__global__ void block_sum_kernel(const int* __restrict__ deg, int* __restrict__ blk, int N) {
    __shared__ int s[SCAN_B];
    int i = blockIdx.x * SCAN_B + threadIdx.x;
    s[threadIdx.x] = (i < N) ? deg[i] : 0;
    __syncthreads();
    for (int off = SCAN_B / 2; off > 0; off >>= 1) {
        if (threadIdx.x < off) s[threadIdx.x] += s[threadIdx.x + off];
        __syncthreads();
    }
    if (threadIdx.x == 0) blk[blockIdx.x] = s[0];
}

// single block, 512 threads: exclusive scan of blk[0..nb), nb <= 512
__global__ void scan_blocks_kernel(int* __restrict__ blk, int nb) {
    __shared__ int s[512];
    int t = threadIdx.x;
    s[t] = (t < nb) ? blk[t] : 0;
    __syncthreads();
    for (int off = 1; off < 512; off <<= 1) {
        int add = (t >= off) ? s[t - off] : 0;
        __syncthreads();
        s[t] += add;
        __syncthreads();
    }
    if (t < nb) blk[t] = (t == 0) ? 0 : s[t - 1];
}

__global__ void row_ofs_kernel(const int* __restrict__ deg, const int* __restrict__ blk_ofs,
                               int* __restrict__ row_ofs, int* __restrict__ cur, int N, int E) {
    __shared__ int s[SCAN_B];
    int t = threadIdx.x;
    int i = blockIdx.x * SCAN_B + t;
    int d = (i < N) ? deg[i] : 0;
    s[t] = d;
    __syncthreads();
    for (int off = 1; off < SCAN_B; off <<= 1) {
        int add = (t >= off) ? s[t - off] : 0;
        __syncthreads();
        s[t] += add;
        __syncthreads();
    }
    int ro = blk_ofs[blockIdx.x] + s[t] - d;  // exclusive prefix
    if (i < N) {
        row_ofs[i] = ro;
        cur[i] = ro;
        if (i == N - 1) row_ofs[N] = E;
    }
}

// fill CSR payload: es[p] = src only (4B — halves random-write line dirtying)
__global__ void fill_kernel(const unsigned* __restrict__ ei, int* __restrict__ cur,
                            int* __restrict__ es, int E) {
    int is64 = detect_is64(ei, E);
    int e = blockIdx.x * blockDim.x + threadIdx.x;
    if (e < E) {
        int s, d;
        if (is64) {
            s = (int)ei[2 * (size_t)e];
            d = (int)ei[2 * (size_t)E + 2 * (size_t)e];
        } else {
            s = (int)ei[e];
            d = (int)ei[(size_t)E + e];
        }
        int p = atomicAdd(&cur[d], 1);
        es[p] = s;
    }
}

// ---------------------------------------------------------------------------
// F=64 gather: wave per node; 4 groups x 16 lanes x float4; 3-deep unroll
// = 12 edge-rows in flight. norm computed from L2-resident dinv table.
// agg[n] = sum_e act(h[src_e])*dinv[s]*dinv[n] + act(h[n])*dinv[n]^2 (+ b)
// ---------------------------------------------------------------------------
template <bool ACT, bool BIAS>
__global__ __launch_bounds__(256) void gather64_kernel(
    const float* __restrict__ h, const int* __restrict__ es,
    const int* __restrict__ row_ofs, const float* __restrict__ dinv,
    const float* __restrict__ b, float* __restrict__ agg, int N) {
    int node = (blockIdx.x * blockDim.x + threadIdx.x) >> 6;
    if (node >= N) return;
    int lane = threadIdx.x & 63;
    int g = lane >> 4, l = lane & 15;
    int beg = row_ofs[node], end = row_ofs[node + 1];
    float dd = dinv[node];

    float4 acc = make_float4(0.f, 0.f, 0.f, 0.f);
    for (int base = beg; base < end; base += 12) {
        int s[3]; float nm[3]; float4 hv[3]; bool v[3];
#pragma unroll
        for (int u = 0; u < 3; ++u) {
            int j = base + 4 * u + g;
            v[u] = j < end;
            s[u] = es[v[u] ? j : beg];
        }
#pragma unroll
        for (int u = 0; u < 3; ++u) {
            nm[u] = v[u] ? dinv[s[u]] * dd : 0.0f;
            hv[u] = *(const float4*)&h[(size_t)s[u] * 64 + 4 * l];
        }
#pragma unroll
        for (int u = 0; u < 3; ++u) {
            float4 hh = hv[u];
            if (ACT) { hh.x = LEAKY(hh.x); hh.y = LEAKY(hh.y); hh.z = LEAKY(hh.z); hh.w = LEAKY(hh.w); }
            acc.x = fmaf(hh.x, nm[u], acc.x); acc.y = fmaf(hh.y, nm[u], acc.y);
            acc.z = fmaf(hh.z, nm[u], acc.z); acc.w = fmaf(hh.w, nm[u], acc.w);
        }
    }
    // butterfly-reduce across the 4 groups (xor 16, 32)
#pragma unroll
    for (int mask = 16; mask <= 32; mask <<= 1) {
        acc.x += __shfl_xor(acc.x, mask);
        acc.y += __shfl_xor(acc.y, mask);
        acc.z += __shfl_xor(acc.z, mask);
        acc.w += __shfl_xor(acc.w, mask);
    }
    if (g == 0) {
        float s2 = dd * dd;
        float4 sv = *(const float4*)&h[(size_t)node * 64 + 4 * l];
        if (ACT) { sv.x = LEAKY(sv.x); sv.y = LEAKY(sv.y); sv.z = LEAKY(sv.z); sv.w = LEAKY(sv.w); }
        acc.x = fmaf(sv.x, s2, acc.x); acc.y = fmaf(sv.y, s2, acc.y);
        acc.z = fmaf(sv.z, s2, acc.z); acc.w = fmaf(sv.w, s2, acc.w);
        if (BIAS) {
            float4 bv = *(const float4*)&b[4 * l];
            acc.x += bv.x; acc.y += bv.y; acc.z += bv.z; acc.w += bv.w;
        }
        *(float4*)&agg[(size_t)node * 64 + 4 * l] = acc;
    }
}

// ---------------------------------------------------------------------------
// F=40 gather: wave per node; 6 groups x 10 lanes x float4 (lanes 60-63 idle);
// 12 edges in flight. Rows are 160B (16B-aligned).
// ---------------------------------------------------------------------------
template <bool ACT, bool BIAS>
__global__ __launch_bounds__(256) void gather40_kernel(
    const float* __restrict__ h, const int* __restrict__ es,
    const int* __restrict__ row_ofs, const float* __restrict__ dinv,
    const float* __restrict__ b, float* __restrict__ agg, int N) {
    int node = (blockIdx.x * blockDim.x + threadIdx.x) >> 6;
    if (node >= N) return;
    int lane = threadIdx.x & 63;
    int g = lane / 10;          // 0..6 (6 => idle lanes 60-63)
    int l = lane - g * 10;      // 0..9
    bool lv = lane < 60;
    int beg = row_ofs[node], end = row_ofs[node + 1];
    float dd = dinv[node];

    float4 acc = make_float4(0.f, 0.f, 0.f, 0.f);
    for (int base = beg; base < end; base += 12) {
        int s[2]; float nm[2]; float4 hv[2]; bool v[2];
#pragma unroll
        for (int u = 0; u < 2; ++u) {
            int j = base + 6 * u + g;
            v[u] = lv && (j < end);
            s[u] = es[v[u] ? j : beg];
        }
#pragma unroll
        for (int u = 0; u < 2; ++u) {
            nm[u] = v[u] ? dinv[s[u]] * dd : 0.0f;
            hv[u] = *(const float4*)&h[(size_t)s[u] * 40 + 4 * l];
        }
#pragma unroll
        for (int u = 0; u < 2; ++u) {
            float4 hh = hv[u];
            if (ACT) { hh.x = LEAKY(hh.x); hh.y = LEAKY(hh.y); hh.z = LEAKY(hh.z); hh.w = LEAKY(hh.w); }
            acc.x = fmaf(hh.x, nm[u], acc.x); acc.y = fmaf(hh.y, nm[u], acc.y);
            acc.z = fmaf(hh.z, nm[u], acc.z); acc.w = fmaf(hh.w, nm[u], acc.w);
        }
    }
    // combine 6 groups: read ORIGINAL acc of lanes +10..+50, then add
    float4 r = acc;
#pragma unroll
    for (int o = 10; o <= 50; o += 10) {
        r.x += __shfl(acc.x, lane + o);
        r.y += __shfl(acc.y, lane + o);
        r.z += __shfl(acc.z, lane + o);
        r.w += __shfl(acc.w, lane + o);
    }
    if (lane < 10) {
        float s2 = dd * dd;
        float4 sv = *(const float4*)&h[(size_t)node * 40 + 4 * l];
        if (ACT) { sv.x = LEAKY(sv.x); sv.y = LEAKY(sv.y); sv.z = LEAKY(sv.z); sv.w = LEAKY(sv.w); }
        r.x = fmaf(sv.x, s2, r.x); r.y = fmaf(sv.y, s2, r.y);
        r.z = fmaf(sv.z, s2, r.z); r.w = fmaf(sv.w, s2, r.w);
        if (BIAS) {
            float4 bv = *(const float4*)&b[4 * l];
            r.x += bv.x; r.y += bv.y; r.z += bv.z; r.w += bv.w;
        }
        *(float4*)&agg[(size_t)node * 40 + 4 * l] = r;
    }
}

// ---------------------------------------------------------------------------
// Register-tiled GEMM: h[n,m] = sum_k act(x[n,k]) * W[k,m] (+ b[m])
// ---------------------------------------------------------------------------
template <int K, int M, bool ACT, bool BIAS>
__global__ __launch_bounds__(256) void gemm_tiled(const float* __restrict__ x,
                                                  const float* __restrict__ W,
                                                  const float* __restrict__ b,
                                                  float* __restrict__ h, int N) {
    constexpr int MT = 4;
    constexpr int MC = (M + MT - 1) / MT;  // thread-columns
    constexpr int MP = MC * MT;            // padded M
    constexpr int NR = 256 / MC;           // row-thread groups per block
    constexpr int NT = 4;                  // nodes per thread
    constexpr int BN = NR * NT;            // nodes per block
    static_assert(K % 4 == 0, "K multiple of 4");

    __shared__ float ws[K * MP];
    for (int i = threadIdx.x; i < K * MP; i += 256) {
        int k = i / MP, m = i - k * MP;
        ws[i] = (m < M) ? W[k * M + m] : 0.0f;
    }
    __syncthreads();

    const int c = threadIdx.x % MC;
    const int r = threadIdx.x / MC;
    if (r >= NR) return;  // no barriers after this point
    const int n0 = blockIdx.x * BN + r * NT;

    float acc[NT][MT];
#pragma unroll
    for (int i = 0; i < NT; ++i)
#pragma unroll
        for (int j = 0; j < MT; ++j) {
            int m = c * MT + j;
            acc[i][j] = (BIAS && m < M) ? b[m] : 0.0f;
        }

    for (int k = 0; k < K; k += 4) {
        float4 wv[4];
#pragma unroll
        for (int kk = 0; kk < 4; ++kk)
            wv[kk] = *(const float4*)&ws[(k + kk) * MP + c * MT];
#pragma unroll
        for (int i = 0; i < NT; ++i) {
            int n = n0 + i;
            if (n < N) {
                float4 xv = *(const float4*)&x[(long long)n * K + k];
                if (ACT) {
                    xv.x = LEAKY(xv.x); xv.y = LEAKY(xv.y);
                    xv.z = LEAKY(xv.z); xv.w = LEAKY(xv.w);
                }
                const float xs[4] = {xv.x, xv.y, xv.z, xv.w};
#pragma unroll
                for (int kk = 0; kk < 4; ++kk) {
                    const float* wp = (const float*)&wv[kk];
#pragma unroll
                    for (int j = 0; j < MT; ++j)
                        acc[i][j] = fmaf(xs[kk], wp[j], acc[i][j]);
                }
            }
        }
    }

#pragma unroll
    for (int i = 0; i < NT; ++i) {
        int n = n0 + i;
        if (n >= N) continue;
        int m = c * MT;
        float* hp = h + (long long)n * M + m;
        if (M % 4 == 0) {
            *(float4*)hp = make_float4(acc[i][0], acc[i][1], acc[i][2], acc[i][3]);
        } else if (m + MT <= M) {
            *(float2*)hp = make_float2(acc[i][0], acc[i][1]);
            *(float2*)(hp + 2) = make_float2(acc[i][2], acc[i][3]);
        } else {
#pragma unroll
            for (int j = 0; j < MT; ++j)
                if (m + j < M) hp[j] = acc[i][j];
        }
    }
}

// ---------------------------------------------------------------------------
// Fused L3-GEMM (40->50, +b3) + leaky + head (50x10, +bl) + log_softmax.
// One node per thread; W3/Wl in LDS (uniform-index broadcast reads).
// ---------------------------------------------------------------------------
__global__ __launch_bounds__(256) void l3head_kernel(
    const float* __restrict__ P, const float* __restrict__ W3,
    const float* __restrict__ b3, const float* __restrict__ Wl,
    const float* __restrict__ bl, float* __restrict__ out, int N) {
    __shared__ float w3s[40 * 50];
    __shared__ float b3s[50];
    __shared__ float wls[50 * 10];
    __shared__ float bls[10];
    for (int i = threadIdx.x; i < 2000; i += 256) w3s[i] = W3[i];
    for (int i = threadIdx.x; i < 500; i += 256) wls[i] = Wl[i];
    if (threadIdx.x < 50) b3s[threadIdx.x] = b3[threadIdx.x];
    if (threadIdx.x < 10) bls[threadIdx.x] = bl[threadIdx.x];
    __syncthreads();
    int n = blockIdx.x * blockDim.x + threadIdx.x;
    if (n >= N) return;

    float p[40];
    const float4* pr = (const float4*)(P + (size_t)n * 40);
#pragma unroll
    for (int q = 0; q < 10; ++q) {
        float4 t = pr[q];
        p[4 * q + 0] = t.x; p[4 * q + 1] = t.y; p[4 * q + 2] = t.z; p[4 * q + 3] = t.w;
    }
    float logits[10];
#pragma unroll
    for (int j = 0; j < 10; ++j) logits[j] = bls[j];
    for (int m = 0; m < 50; ++m) {
        float acc = b3s[m];
#pragma unroll
        for (int k = 0; k < 40; ++k) acc = fmaf(p[k], w3s[k * 50 + m], acc);
        float v = LEAKY(acc);
#pragma unroll
        for (int j = 0; j < 10; ++j) logits[j] = fmaf(v, wls[m * 10 + j], logits[j]);
    }
    float mx = logits[0];
#pragma unroll
    for (int j = 1; j < 10; ++j) mx = fmaxf(mx, logits[j]);
    float s = 0.0f;
#pragma unroll
    for (int j = 0; j < 10; ++j) s += __expf(logits[j] - mx);
    float lse = __logf(s) + mx;
    float* op = out + (size_t)n * 10;
#pragma unroll
    for (int j = 0; j < 10; ++j) op[j] = logits[j] - lse;
}

extern "C" void kernel_launch(void* const* d_in, const int* in_sizes, int n_in,
                              void* d_out, int out_size, void* d_ws, size_t ws_size,
                              hipStream_t stream) {
    const float* x  = (const float*)d_in[0];
    const unsigned* ei = (const unsigned*)d_in[1];
    const float* W1 = (const float*)d_in[2];
    const float* b1 = (const float*)d_in[3];
    const float* W2 = (const float*)d_in[4];
    const float* b2 = (const float*)d_in[5];
    const float* W3 = (const float*)d_in[6];
    const float* b3 = (const float*)d_in[7];
    const float* Wl = (const float*)d_in[8];
    const float* bl = (const float*)d_in[9];
    float* out = (float*)d_out;

    const int N = in_sizes[0] / 64;
    const int E = in_sizes[1] / 2;

    char* wp = (char*)d_ws;
    auto alloc = [&](size_t bytes) {
        char* p = wp;
        wp += (bytes + 255) & ~(size_t)255;
        return p;
    };
    int*   es      = (int*)alloc((size_t)E * 4);
    int*   deg     = (int*)alloc((size_t)N * 4);
    float* dinv    = (float*)alloc((size_t)N * 4);
    int*   row_ofs = (int*)alloc((size_t)(N + 1) * 4);
    int*   cur     = (int*)alloc((size_t)N * 4);
    int*   blk     = (int*)alloc((size_t)512 * 4);
    float* P       = (float*)alloc((size_t)N * 64 * 4);  // narrow scratch (<=64 wide)
    float* A       = (float*)alloc((size_t)N * 80 * 4);  // wide scratch (<=80 wide)

    const int B = 256;
    const int nb = (N + SCAN_B - 1) / SCAN_B;  // <= 512 for N <= 131072

    // ---- CSR build (reused by all 3 layers) ----
    hipMemsetAsync(deg, 0, (size_t)N * 4, stream);
    hist_kernel<<<(E + B - 1) / B, B, 0, stream>>>(ei, deg, E);
    dinv_kernel<<<(N + B - 1) / B, B, 0, stream>>>(deg, dinv, N);
    block_sum_kernel<<<nb, SCAN_B, 0, stream>>>(deg, blk, N);
    scan_blocks_kernel<<<1, 512, 0, stream>>>(blk, nb);
    row_ofs_kernel<<<nb, SCAN_B, 0, stream>>>(deg, blk, row_ofs, cur, N, E);
    fill_kernel<<<(E + B - 1) / B, B, 0, stream>>>(ei, cur, es, E);

    const int gblocks = (N * 64 + B - 1) / B;  // one wave per node

    // block counts for gemm_tiled: BN = (256 / ceil(M/4)) * 4 nodes per block
    auto gb = [&](int M) {
        int MC = (M + 3) / 4;
        int BN = (256 / MC) * 4;
        return (N + BN - 1) / BN;
    };

    // L1: agg(x) first (64-wide < 80-wide), then GEMM(+b1)
    gather64_kernel<false, false><<<gblocks, B, 0, stream>>>(x, es, row_ofs, dinv, nullptr, P, N);
    gemm_tiled<64, 80, false, true><<<gb(80), B, 0, stream>>>(P, W1, b1, A, N);

    // L2: GEMM first (40-wide < 80-wide): H = leaky(A) @ W2, then agg(+b2)
    gemm_tiled<80, 40, true, false><<<gb(40), B, 0, stream>>>(A, W2, nullptr, P, N);
    gather40_kernel<false, true><<<gblocks, B, 0, stream>>>(P, es, row_ofs, dinv, b2, A, N);

    // L3: agg(leaky(A)) first (40-wide < 50-wide), then fused GEMM+head
    gather40_kernel<true, false><<<gblocks, B, 0, stream>>>(A, es, row_ofs, dinv, nullptr, P, N);
    l3head_kernel<<<(N + B - 1) / B, B, 0, stream>>>(P, W3, b3, Wl, bl, out, N);
}

// Round 7
// 363.534 us; speedup vs baseline: 1.2397x; 1.2397x over previous
//
#include <hip/hip_runtime.h>

#define LEAKY(v) ((v) > 0.0f ? (v) : 0.01f * (v))
#define NBUK_MAX 512  // supports N <= 131072 (bucket = dst >> 8)

// ---------------------------------------------------------------------------
// int64-vs-int32 edge_index detection (little-endian, values < 2^31: odd
// 32-bit words of an int64 array are all 0; random int32 src values are not).
// ---------------------------------------------------------------------------
__device__ __forceinline__ int detect_is64(const unsigned* ei, int E) {
    __shared__ int is64_s;
    if (threadIdx.x == 0) {
        int z = 1;
        int limit = 2 * E < 128 ? 2 * E : 128;
        for (int i = 1; i < limit; i += 2)
            if (ei[i] != 0u) { z = 0; break; }
        is64_s = z;
    }
    __syncthreads();
    return is64_s;
}

// ---------------------------------------------------------------------------
// Pass A: decode edge_index -> s32/d32 (coalesced) + per-block bucket counts.
// gcount layout: [bucket][block] (nblk <= 256).
// ---------------------------------------------------------------------------
__global__ __launch_bounds__(256) void bucket_count_kernel(
    const unsigned* __restrict__ ei, int* __restrict__ s32, int* __restrict__ d32,
    int* __restrict__ gcount, int E, int nblk, int nbuk, int ch) {
    __shared__ int hist[NBUK_MAX];
    int is64 = detect_is64(ei, E);
    for (int i = threadIdx.x; i < nbuk; i += 256) hist[i] = 0;
    __syncthreads();
    int base = blockIdx.x * ch;
    int lim = min(base + ch, E);
    for (int e = base + threadIdx.x; e < lim; e += 256) {
        int s, d;
        if (is64) {
            s = (int)ei[2 * (size_t)e];
            d = (int)ei[2 * (size_t)E + 2 * (size_t)e];
        } else {
            s = (int)ei[e];
            d = (int)ei[(size_t)E + e];
        }
        s32[e] = s;
        d32[e] = d;
        atomicAdd(&hist[d >> 8], 1);
    }
    __syncthreads();
    for (int i = threadIdx.x; i < nbuk; i += 256)
        gcount[(size_t)i * nblk + blockIdx.x] = hist[i];
}

// Pass B1: per-bucket totals (one block per bucket).
__global__ __launch_bounds__(256) void bucket_total_kernel(
    const int* __restrict__ gcount, int* __restrict__ btot, int nblk) {
    __shared__ int s[256];
    int sum = 0;
    for (int i = threadIdx.x; i < nblk; i += 256)
        sum += gcount[(size_t)blockIdx.x * nblk + i];
    s[threadIdx.x] = sum;
    __syncthreads();
    for (int off = 128; off > 0; off >>= 1) {
        if (threadIdx.x < off) s[threadIdx.x] += s[threadIdx.x + off];
        __syncthreads();
    }
    if (threadIdx.x == 0) btot[blockIdx.x] = s[0];
}

// Pass B2: exclusive scan of bucket totals -> bbase[0..nbuk], + row_ofs[N]=E.
__global__ __launch_bounds__(512) void scan_btot_kernel(
    const int* __restrict__ btot, int* __restrict__ bbase,
    int* __restrict__ row_ofs, int nbuk, int N, int E) {
    __shared__ int s[512];
    int t = threadIdx.x;
    int v = (t < nbuk) ? btot[t] : 0;
    s[t] = v;
    __syncthreads();
    for (int off = 1; off < 512; off <<= 1) {
        int add = (t >= off) ? s[t - off] : 0;
        __syncthreads();
        s[t] += add;
        __syncthreads();
    }
    if (t < nbuk) bbase[t] = s[t] - v;
    if (t == 0) { bbase[nbuk] = E; row_ofs[N] = E; }
}

// Pass B3: per-bucket exclusive scan of gcount row + bucket base (in place).
__global__ __launch_bounds__(256) void scan_gcount_kernel(
    int* __restrict__ gcount, const int* __restrict__ bbase, int nblk) {
    __shared__ int s[256];
    int t = threadIdx.x;
    int v = (t < nblk) ? gcount[(size_t)blockIdx.x * nblk + t] : 0;
    s[t] = v;
    __syncthreads();
    for (int off = 1; off < 256; off <<= 1) {
        int add = (t >= off) ? s[t - off] : 0;
        __syncthreads();
        s[t] += add;
        __syncthreads();
    }
    if (t < nblk)
        gcount[(size_t)blockIdx.x * nblk + t] = bbase[blockIdx.x] + s[t] - v;
}

// Pass C: scatter edges into bucket-grouped es_tmp={s,d}. LDS atomics only;
// each block writes contiguous per-bucket sub-ranges.
__global__ __launch_bounds__(256) void bucket_scatter_kernel(
    const int* __restrict__ s32, const int* __restrict__ d32,
    const int* __restrict__ gofs, int2* __restrict__ es_tmp,
    int E, int nblk, int nbuk, int ch) {
    __shared__ int cur[NBUK_MAX];
    for (int i = threadIdx.x; i < nbuk; i += 256)
        cur[i] = gofs[(size_t)i * nblk + blockIdx.x];
    __syncthreads();
    int base = blockIdx.x * ch;
    int lim = min(base + ch, E);
    for (int e = base + threadIdx.x; e < lim; e += 256) {
        int s = s32[e], d = d32[e];
        int p = atomicAdd(&cur[d >> 8], 1);
        es_tmp[p] = make_int2(s, d);
    }
}

// Pass D: per-bucket (256 nodes) node-level counting sort. Produces final
// es (src only), row_ofs, and dinv — all without global atomics.
__global__ __launch_bounds__(256) void bucket_sort_kernel(
    const int2* __restrict__ es_tmp, const int* __restrict__ bbase,
    int* __restrict__ es, int* __restrict__ row_ofs, float* __restrict__ dinv,
    int N) {
    __shared__ int hist[256];
    __shared__ int lofs[256];
    int b = blockIdx.x;
    int t = threadIdx.x;
    int beg = bbase[b], end = bbase[b + 1];
    hist[t] = 0;
    __syncthreads();
    for (int j = beg + t; j < end; j += 256)
        atomicAdd(&hist[es_tmp[j].y & 255], 1);
    __syncthreads();
    int v = hist[t];
    lofs[t] = v;
    __syncthreads();
    for (int off = 1; off < 256; off <<= 1) {
        int add = (t >= off) ? lofs[t - off] : 0;
        __syncthreads();
        lofs[t] += add;
        __syncthreads();
    }
    int excl = lofs[t] - v;
    int node = (b << 8) + t;
    if (node <= N) row_ofs[node] = beg + excl;
    if (node < N) dinv[node] = rsqrtf((float)v + 1.0f);
    __syncthreads();
    lofs[t] = beg + excl;  // running cursor
    __syncthreads();
    for (int j = beg + t; j < end; j += 256) {
        int2 ed = es_tmp[j];
        int p = atomicAdd(&lofs[ed.y & 255], 1);
        es[p] = ed.x;
    }
}

// ---------------------------------------------------------------------------
// F=64 gather: wave per node; 4 groups x 16 lanes x float4; 3-deep unroll
// = 12 edge-rows in flight. norm computed from L2-resident dinv table.
// agg[n] = sum_e act(h[src_e])*dinv[s]*dinv[n] + act(h[n])*dinv[n]^2 (+ b)
// ---------------------------------------------------------------------------
template <bool ACT, bool BIAS>
__global__ __launch_bounds__(256) void gather64_kernel(
    const float* __restrict__ h, const int* __restrict__ es,
    const int* __restrict__ row_ofs, const float* __restrict__ dinv,
    const float* __restrict__ b, float* __restrict__ agg, int N) {
    int node = (blockIdx.x * blockDim.x + threadIdx.x) >> 6;
    if (node >= N) return;
    int lane = threadIdx.x & 63;
    int g = lane >> 4, l = lane & 15;
    int beg = row_ofs[node], end = row_ofs[node + 1];
    float dd = dinv[node];

    float4 acc = make_float4(0.f, 0.f, 0.f, 0.f);
    for (int base = beg; base < end; base += 12) {
        int s[3]; float nm[3]; float4 hv[3]; bool v[3];
#pragma unroll
        for (int u = 0; u < 3; ++u) {
            int j = base + 4 * u + g;
            v[u] = j < end;
            s[u] = es[v[u] ? j : beg];
        }
#pragma unroll
        for (int u = 0; u < 3; ++u) {
            nm[u] = v[u] ? dinv[s[u]] * dd : 0.0f;
            hv[u] = *(const float4*)&h[(size_t)s[u] * 64 + 4 * l];
        }
#pragma unroll
        for (int u = 0; u < 3; ++u) {
            float4 hh = hv[u];
            if (ACT) { hh.x = LEAKY(hh.x); hh.y = LEAKY(hh.y); hh.z = LEAKY(hh.z); hh.w = LEAKY(hh.w); }
            acc.x = fmaf(hh.x, nm[u], acc.x); acc.y = fmaf(hh.y, nm[u], acc.y);
            acc.z = fmaf(hh.z, nm[u], acc.z); acc.w = fmaf(hh.w, nm[u], acc.w);
        }
    }
#pragma unroll
    for (int mask = 16; mask <= 32; mask <<= 1) {
        acc.x += __shfl_xor(acc.x, mask);
        acc.y += __shfl_xor(acc.y, mask);
        acc.z += __shfl_xor(acc.z, mask);
        acc.w += __shfl_xor(acc.w, mask);
    }
    if (g == 0) {
        float s2 = dd * dd;
        float4 sv = *(const float4*)&h[(size_t)node * 64 + 4 * l];
        if (ACT) { sv.x = LEAKY(sv.x); sv.y = LEAKY(sv.y); sv.z = LEAKY(sv.z); sv.w = LEAKY(sv.w); }
        acc.x = fmaf(sv.x, s2, acc.x); acc.y = fmaf(sv.y, s2, acc.y);
        acc.z = fmaf(sv.z, s2, acc.z); acc.w = fmaf(sv.w, s2, acc.w);
        if (BIAS) {
            float4 bv = *(const float4*)&b[4 * l];
            acc.x += bv.x; acc.y += bv.y; acc.z += bv.z; acc.w += bv.w;
        }
        *(float4*)&agg[(size_t)node * 64 + 4 * l] = acc;
    }
}

// ---------------------------------------------------------------------------
// F=40 gather: wave per node; 6 groups x 10 lanes x float4 (lanes 60-63 idle);
// 12 edges in flight. Rows are 160B (16B-aligned).
// ---------------------------------------------------------------------------
template <bool ACT, bool BIAS>
__global__ __launch_bounds__(256) void gather40_kernel(
    const float* __restrict__ h, const int* __restrict__ es,
    const int* __restrict__ row_ofs, const float* __restrict__ dinv,
    const float* __restrict__ b, float* __restrict__ agg, int N) {
    int node = (blockIdx.x * blockDim.x + threadIdx.x) >> 6;
    if (node >= N) return;
    int lane = threadIdx.x & 63;
    int g = lane / 10;
    int l = lane - g * 10;
    bool lv = lane < 60;
    int beg = row_ofs[node], end = row_ofs[node + 1];
    float dd = dinv[node];

    float4 acc = make_float4(0.f, 0.f, 0.f, 0.f);
    for (int base = beg; base < end; base += 12) {
        int s[2]; float nm[2]; float4 hv[2]; bool v[2];
#pragma unroll
        for (int u = 0; u < 2; ++u) {
            int j = base + 6 * u + g;
            v[u] = lv && (j < end);
            s[u] = es[v[u] ? j : beg];
        }
#pragma unroll
        for (int u = 0; u < 2; ++u) {
            nm[u] = v[u] ? dinv[s[u]] * dd : 0.0f;
            hv[u] = *(const float4*)&h[(size_t)s[u] * 40 + 4 * l];
        }
#pragma unroll
        for (int u = 0; u < 2; ++u) {
            float4 hh = hv[u];
            if (ACT) { hh.x = LEAKY(hh.x); hh.y = LEAKY(hh.y); hh.z = LEAKY(hh.z); hh.w = LEAKY(hh.w); }
            acc.x = fmaf(hh.x, nm[u], acc.x); acc.y = fmaf(hh.y, nm[u], acc.y);
            acc.z = fmaf(hh.z, nm[u], acc.z); acc.w = fmaf(hh.w, nm[u], acc.w);
        }
    }
    float4 r = acc;
#pragma unroll
    for (int o = 10; o <= 50; o += 10) {
        r.x += __shfl(acc.x, lane + o);
        r.y += __shfl(acc.y, lane + o);
        r.z += __shfl(acc.z, lane + o);
        r.w += __shfl(acc.w, lane + o);
    }
    if (lane < 10) {
        float s2 = dd * dd;
        float4 sv = *(const float4*)&h[(size_t)node * 40 + 4 * l];
        if (ACT) { sv.x = LEAKY(sv.x); sv.y = LEAKY(sv.y); sv.z = LEAKY(sv.z); sv.w = LEAKY(sv.w); }
        r.x = fmaf(sv.x, s2, r.x); r.y = fmaf(sv.y, s2, r.y);
        r.z = fmaf(sv.z, s2, r.z); r.w = fmaf(sv.w, s2, r.w);
        if (BIAS) {
            float4 bv = *(const float4*)&b[4 * l];
            r.x += bv.x; r.y += bv.y; r.z += bv.z; r.w += bv.w;
        }
        *(float4*)&agg[(size_t)node * 40 + 4 * l] = r;
    }
}

// ---------------------------------------------------------------------------
// Register-tiled GEMM: h[n,m] = sum_k act(x[n,k]) * W[k,m] (+ b[m])
// ---------------------------------------------------------------------------
template <int K, int M, bool ACT, bool BIAS>
__global__ __launch_bounds__(256) void gemm_tiled(const float* __restrict__ x,
                                                  const float* __restrict__ W,
                                                  const float* __restrict__ b,
                                                  float* __restrict__ h, int N) {
    constexpr int MT = 4;
    constexpr int MC = (M + MT - 1) / MT;
    constexpr int MP = MC * MT;
    constexpr int NR = 256 / MC;
    constexpr int NT = 4;
    constexpr int BN = NR * NT;
    static_assert(K % 4 == 0, "K multiple of 4");

    __shared__ float ws[K * MP];
    for (int i = threadIdx.x; i < K * MP; i += 256) {
        int k = i / MP, m = i - k * MP;
        ws[i] = (m < M) ? W[k * M + m] : 0.0f;
    }
    __syncthreads();

    const int c = threadIdx.x % MC;
    const int r = threadIdx.x / MC;
    if (r >= NR) return;
    const int n0 = blockIdx.x * BN + r * NT;

    float acc[NT][MT];
#pragma unroll
    for (int i = 0; i < NT; ++i)
#pragma unroll
        for (int j = 0; j < MT; ++j) {
            int m = c * MT + j;
            acc[i][j] = (BIAS && m < M) ? b[m] : 0.0f;
        }

    for (int k = 0; k < K; k += 4) {
        float4 wv[4];
#pragma unroll
        for (int kk = 0; kk < 4; ++kk)
            wv[kk] = *(const float4*)&ws[(k + kk) * MP + c * MT];
#pragma unroll
        for (int i = 0; i < NT; ++i) {
            int n = n0 + i;
            if (n < N) {
                float4 xv = *(const float4*)&x[(long long)n * K + k];
                if (ACT) {
                    xv.x = LEAKY(xv.x); xv.y = LEAKY(xv.y);
                    xv.z = LEAKY(xv.z); xv.w = LEAKY(xv.w);
                }
                const float xs[4] = {xv.x, xv.y, xv.z, xv.w};
#pragma unroll
                for (int kk = 0; kk < 4; ++kk) {
                    const float* wp = (const float*)&wv[kk];
#pragma unroll
                    for (int j = 0; j < MT; ++j)
                        acc[i][j] = fmaf(xs[kk], wp[j], acc[i][j]);
                }
            }
        }
    }

#pragma unroll
    for (int i = 0; i < NT; ++i) {
        int n = n0 + i;
        if (n >= N) continue;
        int m = c * MT;
        float* hp = h + (long long)n * M + m;
        if (M % 4 == 0) {
            *(float4*)hp = make_float4(acc[i][0], acc[i][1], acc[i][2], acc[i][3]);
        } else if (m + MT <= M) {
            *(float2*)hp = make_float2(acc[i][0], acc[i][1]);
            *(float2*)(hp + 2) = make_float2(acc[i][2], acc[i][3]);
        } else {
#pragma unroll
            for (int j = 0; j < MT; ++j)
                if (m + j < M) hp[j] = acc[i][j];
        }
    }
}

// ---------------------------------------------------------------------------
// Fused L3-GEMM (40->50, +b3) + leaky + head (50x10, +bl) + log_softmax.
// ---------------------------------------------------------------------------
__global__ __launch_bounds__(256) void l3head_kernel(
    const float* __restrict__ P, const float* __restrict__ W3,
    const float* __restrict__ b3, const float* __restrict__ Wl,
    const float* __restrict__ bl, float* __restrict__ out, int N) {
    __shared__ float w3s[40 * 50];
    __shared__ float b3s[50];
    __shared__ float wls[50 * 10];
    __shared__ float bls[10];
    for (int i = threadIdx.x; i < 2000; i += 256) w3s[i] = W3[i];
    for (int i = threadIdx.x; i < 500; i += 256) wls[i] = Wl[i];
    if (threadIdx.x < 50) b3s[threadIdx.x] = b3[threadIdx.x];
    if (threadIdx.x < 10) bls[threadIdx.x] = bl[threadIdx.x];
    __syncthreads();
    int n = blockIdx.x * blockDim.x + threadIdx.x;
    if (n >= N) return;

    float p[40];
    const float4* pr = (const float4*)(P + (size_t)n * 40);
#pragma unroll
    for (int q = 0; q < 10; ++q) {
        float4 t = pr[q];
        p[4 * q + 0] = t.x; p[4 * q + 1] = t.y; p[4 * q + 2] = t.z; p[4 * q + 3] = t.w;
    }
    float logits[10];
#pragma unroll
    for (int j = 0; j < 10; ++j) logits[j] = bls[j];
    for (int m = 0; m < 50; ++m) {
        float acc = b3s[m];
#pragma unroll
        for (int k = 0; k < 40; ++k) acc = fmaf(p[k], w3s[k * 50 + m], acc);
        float v = LEAKY(acc);
#pragma unroll
        for (int j = 0; j < 10; ++j) logits[j] = fmaf(v, wls[m * 10 + j], logits[j]);
    }
    float mx = logits[0];
#pragma unroll
    for (int j = 1; j < 10; ++j) mx = fmaxf(mx, logits[j]);
    float s = 0.0f;
#pragma unroll
    for (int j = 0; j < 10; ++j) s += __expf(logits[j] - mx);
    float lse = __logf(s) + mx;
    float* op = out + (size_t)n * 10;
#pragma unroll
    for (int j = 0; j < 10; ++j) op[j] = logits[j] - lse;
}

extern "C" void kernel_launch(void* const* d_in, const int* in_sizes, int n_in,
                              void* d_out, int out_size, void* d_ws, size_t ws_size,
                              hipStream_t stream) {
    const float* x  = (const float*)d_in[0];
    const unsigned* ei = (const unsigned*)d_in[1];
    const float* W1 = (const float*)d_in[2];
    const float* b1 = (const float*)d_in[3];
    const float* W2 = (const float*)d_in[4];
    const float* b2 = (const float*)d_in[5];
    const float* W3 = (const float*)d_in[6];
    const float* b3 = (const float*)d_in[7];
    const float* Wl = (const float*)d_in[8];
    const float* bl = (const float*)d_in[9];
    float* out = (float*)d_out;

    const int N = in_sizes[0] / 64;
    const int E = in_sizes[1] / 2;

    // counting-sort geometry
    int ch = 4096;
    int nblk = (E + ch - 1) / ch;
    if (nblk > 256) { ch = (E + 255) / 256; nblk = (E + ch - 1) / ch; }
    const int nbuk = (N + 255) >> 8;  // <= 512 (N <= 131072)

    char* wp = (char*)d_ws;
    auto alloc = [&](size_t bytes) {
        char* p = wp;
        wp += (bytes + 255) & ~(size_t)255;
        return p;
    };
    int*   es      = (int*)alloc((size_t)E * 4);
    float* dinv    = (float*)alloc((size_t)N * 4);
    int*   row_ofs = (int*)alloc((size_t)(N + 1) * 4);
    int*   gcount  = (int*)alloc((size_t)nbuk * nblk * 4);
    int*   btot    = (int*)alloc((size_t)NBUK_MAX * 4);
    int*   bbase   = (int*)alloc((size_t)(NBUK_MAX + 1) * 4);
    float* P       = (float*)alloc((size_t)N * 64 * 4);  // narrow scratch (<=64 wide)
    float* A       = (float*)alloc((size_t)N * 80 * 4);  // wide scratch (<=80 wide)
    // aliases: dead before first real use of their hosts
    int*   s32     = (int*)P;             // pass A-C only; P first written by gather64
    int*   d32     = (int*)P + E;
    int2*  es_tmp  = (int2*)A;            // pass C-D only; A first written by gemm1

    const int B = 256;

    // ---- CSR build: atomic-free two-level counting sort ----
    bucket_count_kernel<<<nblk, B, 0, stream>>>(ei, s32, d32, gcount, E, nblk, nbuk, ch);
    bucket_total_kernel<<<nbuk, B, 0, stream>>>(gcount, btot, nblk);
    scan_btot_kernel<<<1, 512, 0, stream>>>(btot, bbase, row_ofs, nbuk, N, E);
    scan_gcount_kernel<<<nbuk, B, 0, stream>>>(gcount, bbase, nblk);
    bucket_scatter_kernel<<<nblk, B, 0, stream>>>(s32, d32, gcount, es_tmp, E, nblk, nbuk, ch);
    bucket_sort_kernel<<<nbuk, B, 0, stream>>>(es_tmp, bbase, es, row_ofs, dinv, N);

    const int gblocks = (N * 64 + B - 1) / B;  // one wave per node

    auto gb = [&](int M) {
        int MC = (M + 3) / 4;
        int BN = (256 / MC) * 4;
        return (N + BN - 1) / BN;
    };

    // L1: agg(x) first (64-wide < 80-wide), then GEMM(+b1)
    gather64_kernel<false, false><<<gblocks, B, 0, stream>>>(x, es, row_ofs, dinv, nullptr, P, N);
    gemm_tiled<64, 80, false, true><<<gb(80), B, 0, stream>>>(P, W1, b1, A, N);

    // L2: GEMM first (40-wide < 80-wide): H = leaky(A) @ W2, then agg(+b2)
    gemm_tiled<80, 40, true, false><<<gb(40), B, 0, stream>>>(A, W2, nullptr, P, N);
    gather40_kernel<false, true><<<gblocks, B, 0, stream>>>(P, es, row_ofs, dinv, b2, A, N);

    // L3: agg(leaky(A)) first (40-wide < 50-wide), then fused GEMM+head
    gather40_kernel<true, false><<<gblocks, B, 0, stream>>>(A, es, row_ofs, dinv, nullptr, P, N);
    l3head_kernel<<<(N + B - 1) / B, B, 0, stream>>>(P, W3, b3, Wl, bl, out, N);
}

// Round 8
// 353.021 us; speedup vs baseline: 1.2766x; 1.0298x over previous
//
#include <hip/hip_runtime.h>

#define LEAKY(v) ((v) > 0.0f ? (v) : 0.01f * (v))
#define NBUK_MAX 512  // supports N <= 131072 (bucket = dst >> 8)

// ---- bf16 helpers (manual: avoids header type friction) --------------------
__device__ __forceinline__ unsigned short f2bf(float f) {
    unsigned u = __float_as_uint(f);
    u += 0x7fffu + ((u >> 16) & 1u);  // round-to-nearest-even
    return (unsigned short)(u >> 16);
}
__device__ __forceinline__ float4 bf4_to_f4(uint2 u) {
    float4 r;
    r.x = __uint_as_float(u.x << 16);
    r.y = __uint_as_float(u.x & 0xffff0000u);
    r.z = __uint_as_float(u.y << 16);
    r.w = __uint_as_float(u.y & 0xffff0000u);
    return r;
}

// ---------------------------------------------------------------------------
// int64-vs-int32 edge_index detection (little-endian, values < 2^31: odd
// 32-bit words of an int64 array are all 0; random int32 src values are not).
// ---------------------------------------------------------------------------
__device__ __forceinline__ int detect_is64(const unsigned* ei, int E) {
    __shared__ int is64_s;
    if (threadIdx.x == 0) {
        int z = 1;
        int limit = 2 * E < 128 ? 2 * E : 128;
        for (int i = 1; i < limit; i += 2)
            if (ei[i] != 0u) { z = 0; break; }
        is64_s = z;
    }
    __syncthreads();
    return is64_s;
}

// fp32 -> bf16 conversion pass (x -> xb), float4 in / ushort4 out
__global__ __launch_bounds__(256) void cvt_bf16_kernel(
    const float* __restrict__ x, ushort4* __restrict__ xb, int nq) {
    int i = blockIdx.x * 256 + threadIdx.x;
    if (i < nq) {
        float4 v = ((const float4*)x)[i];
        ushort4 o;
        o.x = f2bf(v.x); o.y = f2bf(v.y); o.z = f2bf(v.z); o.w = f2bf(v.w);
        xb[i] = o;
    }
}

// ---------------------------------------------------------------------------
// Pass A: decode edge_index -> s32/d32 (coalesced) + per-block bucket counts.
// ---------------------------------------------------------------------------
__global__ __launch_bounds__(256) void bucket_count_kernel(
    const unsigned* __restrict__ ei, int* __restrict__ s32, int* __restrict__ d32,
    int* __restrict__ gcount, int E, int nblk, int nbuk, int ch) {
    __shared__ int hist[NBUK_MAX];
    int is64 = detect_is64(ei, E);
    for (int i = threadIdx.x; i < nbuk; i += 256) hist[i] = 0;
    __syncthreads();
    int base = blockIdx.x * ch;
    int lim = min(base + ch, E);
    for (int e = base + threadIdx.x; e < lim; e += 256) {
        int s, d;
        if (is64) {
            s = (int)ei[2 * (size_t)e];
            d = (int)ei[2 * (size_t)E + 2 * (size_t)e];
        } else {
            s = (int)ei[e];
            d = (int)ei[(size_t)E + e];
        }
        s32[e] = s;
        d32[e] = d;
        atomicAdd(&hist[d >> 8], 1);
    }
    __syncthreads();
    for (int i = threadIdx.x; i < nbuk; i += 256)
        gcount[(size_t)i * nblk + blockIdx.x] = hist[i];
}

// Pass B1: per-bucket totals.
__global__ __launch_bounds__(256) void bucket_total_kernel(
    const int* __restrict__ gcount, int* __restrict__ btot, int nblk) {
    __shared__ int s[256];
    int sum = 0;
    for (int i = threadIdx.x; i < nblk; i += 256)
        sum += gcount[(size_t)blockIdx.x * nblk + i];
    s[threadIdx.x] = sum;
    __syncthreads();
    for (int off = 128; off > 0; off >>= 1) {
        if (threadIdx.x < off) s[threadIdx.x] += s[threadIdx.x + off];
        __syncthreads();
    }
    if (threadIdx.x == 0) btot[blockIdx.x] = s[0];
}

// Pass B2: exclusive scan of bucket totals -> bbase[0..nbuk], + row_ofs[N]=E.
__global__ __launch_bounds__(512) void scan_btot_kernel(
    const int* __restrict__ btot, int* __restrict__ bbase,
    int* __restrict__ row_ofs, int nbuk, int N, int E) {
    __shared__ int s[512];
    int t = threadIdx.x;
    int v = (t < nbuk) ? btot[t] : 0;
    s[t] = v;
    __syncthreads();
    for (int off = 1; off < 512; off <<= 1) {
        int add = (t >= off) ? s[t - off] : 0;
        __syncthreads();
        s[t] += add;
        __syncthreads();
    }
    if (t < nbuk) bbase[t] = s[t] - v;
    if (t == 0) { bbase[nbuk] = E; row_ofs[N] = E; }
}

// Pass B3: per-bucket exclusive scan of gcount row + bucket base (in place).
__global__ __launch_bounds__(256) void scan_gcount_kernel(
    int* __restrict__ gcount, const int* __restrict__ bbase, int nblk) {
    __shared__ int s[256];
    int t = threadIdx.x;
    int v = (t < nblk) ? gcount[(size_t)blockIdx.x * nblk + t] : 0;
    s[t] = v;
    __syncthreads();
    for (int off = 1; off < 256; off <<= 1) {
        int add = (t >= off) ? s[t - off] : 0;
        __syncthreads();
        s[t] += add;
        __syncthreads();
    }
    if (t < nblk)
        gcount[(size_t)blockIdx.x * nblk + t] = bbase[blockIdx.x] + s[t] - v;
}

// Pass C: scatter edges into bucket-grouped es_tmp={s,d}. LDS atomics only.
__global__ __launch_bounds__(256) void bucket_scatter_kernel(
    const int* __restrict__ s32, const int* __restrict__ d32,
    const int* __restrict__ gofs, int2* __restrict__ es_tmp,
    int E, int nblk, int nbuk, int ch) {
    __shared__ int cur[NBUK_MAX];
    for (int i = threadIdx.x; i < nbuk; i += 256)
        cur[i] = gofs[(size_t)i * nblk + blockIdx.x];
    __syncthreads();
    int base = blockIdx.x * ch;
    int lim = min(base + ch, E);
    for (int e = base + threadIdx.x; e < lim; e += 256) {
        int s = s32[e], d = d32[e];
        int p = atomicAdd(&cur[d >> 8], 1);
        es_tmp[p] = make_int2(s, d);
    }
}

// Pass D: per-bucket node-level counting sort -> es, row_ofs, dinv.
__global__ __launch_bounds__(256) void bucket_sort_kernel(
    const int2* __restrict__ es_tmp, const int* __restrict__ bbase,
    int* __restrict__ es, int* __restrict__ row_ofs, float* __restrict__ dinv,
    int N) {
    __shared__ int hist[256];
    __shared__ int lofs[256];
    int b = blockIdx.x;
    int t = threadIdx.x;
    int beg = bbase[b], end = bbase[b + 1];
    hist[t] = 0;
    __syncthreads();
    for (int j = beg + t; j < end; j += 256)
        atomicAdd(&hist[es_tmp[j].y & 255], 1);
    __syncthreads();
    int v = hist[t];
    lofs[t] = v;
    __syncthreads();
    for (int off = 1; off < 256; off <<= 1) {
        int add = (t >= off) ? lofs[t - off] : 0;
        __syncthreads();
        lofs[t] += add;
        __syncthreads();
    }
    int excl = lofs[t] - v;
    int node = (b << 8) + t;
    if (node <= N) row_ofs[node] = beg + excl;
    if (node < N) dinv[node] = rsqrtf((float)v + 1.0f);
    __syncthreads();
    lofs[t] = beg + excl;  // running cursor
    __syncthreads();
    for (int j = beg + t; j < end; j += 256) {
        int2 ed = es_tmp[j];
        int p = atomicAdd(&lofs[ed.y & 255], 1);
        es[p] = ed.x;
    }
}

// ---------------------------------------------------------------------------
// F=64 bf16 gather: wave per node; 4 groups x 16 lanes x uint2 (4 bf16);
// 4-deep unroll = 16 edge-rows in flight. Output fp32.
// ---------------------------------------------------------------------------
__global__ __launch_bounds__(256) void gather64_bf16_kernel(
    const unsigned short* __restrict__ hb, const int* __restrict__ es,
    const int* __restrict__ row_ofs, const float* __restrict__ dinv,
    float* __restrict__ agg, int N) {
    int node = (blockIdx.x * blockDim.x + threadIdx.x) >> 6;
    if (node >= N) return;
    int lane = threadIdx.x & 63;
    int g = lane >> 4, l = lane & 15;
    int beg = row_ofs[node], end = row_ofs[node + 1];
    float dd = dinv[node];

    float4 acc = make_float4(0.f, 0.f, 0.f, 0.f);
    for (int base = beg; base < end; base += 16) {
        int s[4]; float nm[4]; uint2 hv[4]; bool v[4];
#pragma unroll
        for (int u = 0; u < 4; ++u) {
            int j = base + 4 * u + g;
            v[u] = j < end;
            s[u] = es[v[u] ? j : beg];
        }
#pragma unroll
        for (int u = 0; u < 4; ++u) {
            nm[u] = v[u] ? dinv[s[u]] * dd : 0.0f;
            hv[u] = *(const uint2*)&hb[(size_t)s[u] * 64 + 4 * l];
        }
#pragma unroll
        for (int u = 0; u < 4; ++u) {
            float4 hh = bf4_to_f4(hv[u]);
            acc.x = fmaf(hh.x, nm[u], acc.x); acc.y = fmaf(hh.y, nm[u], acc.y);
            acc.z = fmaf(hh.z, nm[u], acc.z); acc.w = fmaf(hh.w, nm[u], acc.w);
        }
    }
#pragma unroll
    for (int mask = 16; mask <= 32; mask <<= 1) {
        acc.x += __shfl_xor(acc.x, mask);
        acc.y += __shfl_xor(acc.y, mask);
        acc.z += __shfl_xor(acc.z, mask);
        acc.w += __shfl_xor(acc.w, mask);
    }
    if (g == 0) {
        float s2 = dd * dd;
        float4 sv = bf4_to_f4(*(const uint2*)&hb[(size_t)node * 64 + 4 * l]);
        acc.x = fmaf(sv.x, s2, acc.x); acc.y = fmaf(sv.y, s2, acc.y);
        acc.z = fmaf(sv.z, s2, acc.z); acc.w = fmaf(sv.w, s2, acc.w);
        *(float4*)&agg[(size_t)node * 64 + 4 * l] = acc;
    }
}

// ---------------------------------------------------------------------------
// F=40 bf16 gather: wave per node; 6 groups x 10 lanes x uint2 (lanes 60-63
// idle); 3-deep = 18 edges in flight. Input act is pre-applied upstream.
// OUTLEAKY_BF16: apply bias+leaky, store bf16. Else: fp32 store (+no act).
// ---------------------------------------------------------------------------
template <bool BIAS, bool OUTLEAKY_BF16>
__global__ __launch_bounds__(256) void gather40_bf16_kernel(
    const unsigned short* __restrict__ hb, const int* __restrict__ es,
    const int* __restrict__ row_ofs, const float* __restrict__ dinv,
    const float* __restrict__ b, void* __restrict__ aggv, int N) {
    int node = (blockIdx.x * blockDim.x + threadIdx.x) >> 6;
    if (node >= N) return;
    int lane = threadIdx.x & 63;
    int g = lane / 10;
    int l = lane - g * 10;
    bool lv = lane < 60;
    int beg = row_ofs[node], end = row_ofs[node + 1];
    float dd = dinv[node];

    float4 acc = make_float4(0.f, 0.f, 0.f, 0.f);
    for (int base = beg; base < end; base += 18) {
        int s[3]; float nm[3]; uint2 hv[3]; bool v[3];
#pragma unroll
        for (int u = 0; u < 3; ++u) {
            int j = base + 6 * u + g;
            v[u] = lv && (j < end);
            s[u] = es[v[u] ? j : beg];
        }
#pragma unroll
        for (int u = 0; u < 3; ++u) {
            nm[u] = v[u] ? dinv[s[u]] * dd : 0.0f;
            hv[u] = *(const uint2*)&hb[(size_t)s[u] * 40 + 4 * l];
        }
#pragma unroll
        for (int u = 0; u < 3; ++u) {
            float4 hh = bf4_to_f4(hv[u]);
            acc.x = fmaf(hh.x, nm[u], acc.x); acc.y = fmaf(hh.y, nm[u], acc.y);
            acc.z = fmaf(hh.z, nm[u], acc.z); acc.w = fmaf(hh.w, nm[u], acc.w);
        }
    }
    float4 r = acc;
#pragma unroll
    for (int o = 10; o <= 50; o += 10) {
        r.x += __shfl(acc.x, lane + o);
        r.y += __shfl(acc.y, lane + o);
        r.z += __shfl(acc.z, lane + o);
        r.w += __shfl(acc.w, lane + o);
    }
    if (lane < 10) {
        float s2 = dd * dd;
        float4 sv = bf4_to_f4(*(const uint2*)&hb[(size_t)node * 40 + 4 * l]);
        r.x = fmaf(sv.x, s2, r.x); r.y = fmaf(sv.y, s2, r.y);
        r.z = fmaf(sv.z, s2, r.z); r.w = fmaf(sv.w, s2, r.w);
        if (BIAS) {
            float4 bv = *(const float4*)&b[4 * l];
            r.x += bv.x; r.y += bv.y; r.z += bv.z; r.w += bv.w;
        }
        if (OUTLEAKY_BF16) {
            r.x = LEAKY(r.x); r.y = LEAKY(r.y); r.z = LEAKY(r.z); r.w = LEAKY(r.w);
            ushort4 o;
            o.x = f2bf(r.x); o.y = f2bf(r.y); o.z = f2bf(r.z); o.w = f2bf(r.w);
            *(ushort4*)&((unsigned short*)aggv)[(size_t)node * 40 + 4 * l] = o;
        } else {
            *(float4*)&((float*)aggv)[(size_t)node * 40 + 4 * l] = r;
        }
    }
}

// ---------------------------------------------------------------------------
// Register-tiled GEMM: h[n,m] = sum_k act(x[n,k]) * W[k,m] (+ b[m]).
// OUT_BF16 (requires M%4==0): pack 4 bf16 per store.
// ---------------------------------------------------------------------------
template <int K, int M, bool ACT, bool BIAS, bool OUT_BF16>
__global__ __launch_bounds__(256) void gemm_tiled(const float* __restrict__ x,
                                                  const float* __restrict__ W,
                                                  const float* __restrict__ b,
                                                  void* __restrict__ hv, int N) {
    constexpr int MT = 4;
    constexpr int MC = (M + MT - 1) / MT;
    constexpr int MP = MC * MT;
    constexpr int NR = 256 / MC;
    constexpr int NT = 4;
    constexpr int BN = NR * NT;
    static_assert(K % 4 == 0, "K multiple of 4");
    static_assert(!OUT_BF16 || M % 4 == 0, "bf16 out needs M%4==0");

    __shared__ float ws[K * MP];
    for (int i = threadIdx.x; i < K * MP; i += 256) {
        int k = i / MP, m = i - k * MP;
        ws[i] = (m < M) ? W[k * M + m] : 0.0f;
    }
    __syncthreads();

    const int c = threadIdx.x % MC;
    const int r = threadIdx.x / MC;
    if (r >= NR) return;
    const int n0 = blockIdx.x * BN + r * NT;

    float acc[NT][MT];
#pragma unroll
    for (int i = 0; i < NT; ++i)
#pragma unroll
        for (int j = 0; j < MT; ++j) {
            int m = c * MT + j;
            acc[i][j] = (BIAS && m < M) ? b[m] : 0.0f;
        }

    for (int k = 0; k < K; k += 4) {
        float4 wv[4];
#pragma unroll
        for (int kk = 0; kk < 4; ++kk)
            wv[kk] = *(const float4*)&ws[(k + kk) * MP + c * MT];
#pragma unroll
        for (int i = 0; i < NT; ++i) {
            int n = n0 + i;
            if (n < N) {
                float4 xv = *(const float4*)&x[(long long)n * K + k];
                if (ACT) {
                    xv.x = LEAKY(xv.x); xv.y = LEAKY(xv.y);
                    xv.z = LEAKY(xv.z); xv.w = LEAKY(xv.w);
                }
                const float xs[4] = {xv.x, xv.y, xv.z, xv.w};
#pragma unroll
                for (int kk = 0; kk < 4; ++kk) {
                    const float* wp = (const float*)&wv[kk];
#pragma unroll
                    for (int j = 0; j < MT; ++j)
                        acc[i][j] = fmaf(xs[kk], wp[j], acc[i][j]);
                }
            }
        }
    }

#pragma unroll
    for (int i = 0; i < NT; ++i) {
        int n = n0 + i;
        if (n >= N) continue;
        int m = c * MT;
        if (OUT_BF16) {
            ushort4 o;
            o.x = f2bf(acc[i][0]); o.y = f2bf(acc[i][1]);
            o.z = f2bf(acc[i][2]); o.w = f2bf(acc[i][3]);
            *(ushort4*)&((unsigned short*)hv)[(long long)n * M + m] = o;
        } else {
            float* hp = (float*)hv + (long long)n * M + m;
            if (M % 4 == 0) {
                *(float4*)hp = make_float4(acc[i][0], acc[i][1], acc[i][2], acc[i][3]);
            } else if (m + MT <= M) {
                *(float2*)hp = make_float2(acc[i][0], acc[i][1]);
                *(float2*)(hp + 2) = make_float2(acc[i][2], acc[i][3]);
            } else {
#pragma unroll
                for (int j = 0; j < MT; ++j)
                    if (m + j < M) hp[j] = acc[i][j];
            }
        }
    }
}

// ---------------------------------------------------------------------------
// Fused L3-GEMM (40->50, +b3) + leaky + head (50x10, +bl) + log_softmax.
// ---------------------------------------------------------------------------
__global__ __launch_bounds__(256) void l3head_kernel(
    const float* __restrict__ P, const float* __restrict__ W3,
    const float* __restrict__ b3, const float* __restrict__ Wl,
    const float* __restrict__ bl, float* __restrict__ out, int N) {
    __shared__ float w3s[40 * 50];
    __shared__ float b3s[50];
    __shared__ float wls[50 * 10];
    __shared__ float bls[10];
    for (int i = threadIdx.x; i < 2000; i += 256) w3s[i] = W3[i];
    for (int i = threadIdx.x; i < 500; i += 256) wls[i] = Wl[i];
    if (threadIdx.x < 50) b3s[threadIdx.x] = b3[threadIdx.x];
    if (threadIdx.x < 10) bls[threadIdx.x] = bl[threadIdx.x];
    __syncthreads();
    int n = blockIdx.x * blockDim.x + threadIdx.x;
    if (n >= N) return;

    float p[40];
    const float4* pr = (const float4*)(P + (size_t)n * 40);
#pragma unroll
    for (int q = 0; q < 10; ++q) {
        float4 t = pr[q];
        p[4 * q + 0] = t.x; p[4 * q + 1] = t.y; p[4 * q + 2] = t.z; p[4 * q + 3] = t.w;
    }
    float logits[10];
#pragma unroll
    for (int j = 0; j < 10; ++j) logits[j] = bls[j];
    for (int m = 0; m < 50; ++m) {
        float acc = b3s[m];
#pragma unroll
        for (int k = 0; k < 40; ++k) acc = fmaf(p[k], w3s[k * 50 + m], acc);
        float v = LEAKY(acc);
#pragma unroll
        for (int j = 0; j < 10; ++j) logits[j] = fmaf(v, wls[m * 10 + j], logits[j]);
    }
    float mx = logits[0];
#pragma unroll
    for (int j = 1; j < 10; ++j) mx = fmaxf(mx, logits[j]);
    float s = 0.0f;
#pragma unroll
    for (int j = 0; j < 10; ++j) s += __expf(logits[j] - mx);
    float lse = __logf(s) + mx;
    float* op = out + (size_t)n * 10;
#pragma unroll
    for (int j = 0; j < 10; ++j) op[j] = logits[j] - lse;
}

extern "C" void kernel_launch(void* const* d_in, const int* in_sizes, int n_in,
                              void* d_out, int out_size, void* d_ws, size_t ws_size,
                              hipStream_t stream) {
    const float* x  = (const float*)d_in[0];
    const unsigned* ei = (const unsigned*)d_in[1];
    const float* W1 = (const float*)d_in[2];
    const float* b1 = (const float*)d_in[3];
    const float* W2 = (const float*)d_in[4];
    const float* b2 = (const float*)d_in[5];
    const float* W3 = (const float*)d_in[6];
    const float* b3 = (const float*)d_in[7];
    const float* Wl = (const float*)d_in[8];
    const float* bl = (const float*)d_in[9];
    float* out = (float*)d_out;

    const int N = in_sizes[0] / 64;
    const int E = in_sizes[1] / 2;

    // counting-sort geometry
    int ch = 4096;
    int nblk = (E + ch - 1) / ch;
    if (nblk > 256) { ch = (E + 255) / 256; nblk = (E + ch - 1) / ch; }
    const int nbuk = (N + 255) >> 8;  // <= 512 (N <= 131072)

    char* wp = (char*)d_ws;
    auto alloc = [&](size_t bytes) {
        char* p = wp;
        wp += (bytes + 255) & ~(size_t)255;
        return p;
    };
    int*   es      = (int*)alloc((size_t)E * 4);
    float* dinv    = (float*)alloc((size_t)N * 4);
    int*   row_ofs = (int*)alloc((size_t)(N + 1) * 4);
    int*   gcount  = (int*)alloc((size_t)nbuk * nblk * 4);
    int*   btot    = (int*)alloc((size_t)NBUK_MAX * 4);
    int*   bbase   = (int*)alloc((size_t)(NBUK_MAX + 1) * 4);
    float* P       = (float*)alloc((size_t)N * 64 * 4);  // 25.6 MB region
    float* A       = (float*)alloc((size_t)N * 80 * 4);  // 32 MB region

    // aliases (all uses strictly sequential; host regions dead at alias use):
    int*   s32    = (int*)P;                    // passes A-C; P written by gather64 later
    int*   d32    = (int*)P + E;
    int2*  es_tmp = (int2*)A;                   // passes C-D (E*8 bytes)
    // xb: bf16 x copy, N*64*2 bytes, placed after es_tmp inside A
    size_t xb_off = (((size_t)E * 8) + 255) & ~(size_t)255;
    unsigned short* xb = (unsigned short*)((char*)A + xb_off);  // dead once gemm1 writes A
    // Pb: bf16 gemm2 output (N*40*2) at tail of P (beyond fp32 N*40*4 output)
    size_t pb_off = (((size_t)N * 64 * 4) - ((size_t)N * 40 * 2)) & ~(size_t)255;
    unsigned short* Pb = (unsigned short*)((char*)P + pb_off);
    // Ab: bf16 leaky(conv2-out) (N*40*2) at tail of A (A fp32 dead after gemm2)
    size_t ab_off = (((size_t)N * 80 * 4) - ((size_t)N * 40 * 2)) & ~(size_t)255;
    unsigned short* Ab = (unsigned short*)((char*)A + ab_off);

    const int B = 256;

    // x -> bf16 copy (used by gather64)
    cvt_bf16_kernel<<<(N * 16 + B - 1) / B, B, 0, stream>>>(x, (ushort4*)xb, N * 16);

    // ---- CSR build: atomic-free two-level counting sort ----
    bucket_count_kernel<<<nblk, B, 0, stream>>>(ei, s32, d32, gcount, E, nblk, nbuk, ch);
    bucket_total_kernel<<<nbuk, B, 0, stream>>>(gcount, btot, nblk);
    scan_btot_kernel<<<1, 512, 0, stream>>>(btot, bbase, row_ofs, nbuk, N, E);
    scan_gcount_kernel<<<nbuk, B, 0, stream>>>(gcount, bbase, nblk);
    bucket_scatter_kernel<<<nblk, B, 0, stream>>>(s32, d32, gcount, es_tmp, E, nblk, nbuk, ch);
    bucket_sort_kernel<<<nbuk, B, 0, stream>>>(es_tmp, bbase, es, row_ofs, dinv, N);

    const int gblocks = (N * 64 + B - 1) / B;  // one wave per node

    auto gb = [&](int M) {
        int MC = (M + 3) / 4;
        int BN = (256 / MC) * 4;
        return (N + BN - 1) / BN;
    };

    // L1: agg(xb) (bf16 gather), then GEMM(+b1) fp32
    gather64_bf16_kernel<<<gblocks, B, 0, stream>>>(xb, es, row_ofs, dinv, P, N);
    gemm_tiled<64, 80, false, true, false><<<gb(80), B, 0, stream>>>(P, W1, b1, A, N);

    // L2: GEMM first (40 < 80): Pb = bf16(leaky(A) @ W2); agg(+b2) -> leaky -> Ab (bf16)
    gemm_tiled<80, 40, true, false, true><<<gb(40), B, 0, stream>>>(A, W2, nullptr, Pb, N);
    gather40_bf16_kernel<true, true><<<gblocks, B, 0, stream>>>(Pb, es, row_ofs, dinv, b2, Ab, N);

    // L3: agg(Ab) (act pre-applied) -> P fp32, then fused GEMM+head
    gather40_bf16_kernel<false, false><<<gblocks, B, 0, stream>>>(Ab, es, row_ofs, dinv, nullptr, P, N);
    l3head_kernel<<<(N + B - 1) / B, B, 0, stream>>>(P, W3, b3, Wl, bl, out, N);
}

// Round 10
// 324.612 us; speedup vs baseline: 1.3883x; 1.0875x over previous
//
#include <hip/hip_runtime.h>

#define LEAKY(v) ((v) > 0.0f ? (v) : 0.01f * (v))
#define NBUK_MAX 512  // supports N <= 131072 (bucket = dst >> 8)

// ---- bf16 helpers (manual: avoids header type friction) --------------------
__device__ __forceinline__ unsigned short f2bf(float f) {
    unsigned u = __float_as_uint(f);
    u += 0x7fffu + ((u >> 16) & 1u);  // round-to-nearest-even
    return (unsigned short)(u >> 16);
}
__device__ __forceinline__ float4 bf4_to_f4(uint2 u) {
    float4 r;
    r.x = __uint_as_float(u.x << 16);
    r.y = __uint_as_float(u.x & 0xffff0000u);
    r.z = __uint_as_float(u.y << 16);
    r.w = __uint_as_float(u.y & 0xffff0000u);
    return r;
}

// ---------------------------------------------------------------------------
// int64-vs-int32 edge_index detection.
// ---------------------------------------------------------------------------
__device__ __forceinline__ int detect_is64(const unsigned* ei, int E) {
    __shared__ int is64_s;
    if (threadIdx.x == 0) {
        int z = 1;
        int limit = 2 * E < 128 ? 2 * E : 128;
        for (int i = 1; i < limit; i += 2)
            if (ei[i] != 0u) { z = 0; break; }
        is64_s = z;
    }
    __syncthreads();
    return is64_s;
}

// x -> bf16(x * dinv[node]) ; 16 quads (64 floats) per node
__global__ __launch_bounds__(256) void cvt_scale_kernel(
    const float* __restrict__ x, const float* __restrict__ dinv,
    ushort4* __restrict__ xb, int N) {
    int i = blockIdx.x * 256 + threadIdx.x;  // quad index
    int n = i >> 4;
    if (n >= N) return;
    float dn = dinv[n];
    float4 v = ((const float4*)x)[i];
    ushort4 o;
    o.x = f2bf(v.x * dn); o.y = f2bf(v.y * dn);
    o.z = f2bf(v.z * dn); o.w = f2bf(v.w * dn);
    xb[i] = o;
}

// ---------------------------------------------------------------------------
// Pass A: decode edge_index -> s32/d32 (coalesced) + per-block bucket counts.
// ---------------------------------------------------------------------------
__global__ __launch_bounds__(256) void bucket_count_kernel(
    const unsigned* __restrict__ ei, int* __restrict__ s32, int* __restrict__ d32,
    int* __restrict__ gcount, int E, int nblk, int nbuk, int ch) {
    __shared__ int hist[NBUK_MAX];
    int is64 = detect_is64(ei, E);
    for (int i = threadIdx.x; i < nbuk; i += 256) hist[i] = 0;
    __syncthreads();
    int base = blockIdx.x * ch;
    int lim = min(base + ch, E);
    for (int e = base + threadIdx.x; e < lim; e += 256) {
        int s, d;
        if (is64) {
            s = (int)ei[2 * (size_t)e];
            d = (int)ei[2 * (size_t)E + 2 * (size_t)e];
        } else {
            s = (int)ei[e];
            d = (int)ei[(size_t)E + e];
        }
        s32[e] = s;
        d32[e] = d;
        atomicAdd(&hist[d >> 8], 1);
    }
    __syncthreads();
    for (int i = threadIdx.x; i < nbuk; i += 256)
        gcount[(size_t)i * nblk + blockIdx.x] = hist[i];
}

// Pass B1: per-bucket totals.
__global__ __launch_bounds__(256) void bucket_total_kernel(
    const int* __restrict__ gcount, int* __restrict__ btot, int nblk) {
    __shared__ int s[256];
    int sum = 0;
    for (int i = threadIdx.x; i < nblk; i += 256)
        sum += gcount[(size_t)blockIdx.x * nblk + i];
    s[threadIdx.x] = sum;
    __syncthreads();
    for (int off = 128; off > 0; off >>= 1) {
        if (threadIdx.x < off) s[threadIdx.x] += s[threadIdx.x + off];
        __syncthreads();
    }
    if (threadIdx.x == 0) btot[blockIdx.x] = s[0];
}

// Pass B2: exclusive scan of bucket totals -> bbase[0..nbuk], + row_ofs[N]=E.
__global__ __launch_bounds__(512) void scan_btot_kernel(
    const int* __restrict__ btot, int* __restrict__ bbase,
    int* __restrict__ row_ofs, int nbuk, int N, int E) {
    __shared__ int s[512];
    int t = threadIdx.x;
    int v = (t < nbuk) ? btot[t] : 0;
    s[t] = v;
    __syncthreads();
    for (int off = 1; off < 512; off <<= 1) {
        int add = (t >= off) ? s[t - off] : 0;
        __syncthreads();
        s[t] += add;
        __syncthreads();
    }
    if (t < nbuk) bbase[t] = s[t] - v;
    if (t == 0) { bbase[nbuk] = E; row_ofs[N] = E; }
}

// Pass B3: per-bucket exclusive scan of gcount row + bucket base (in place).
__global__ __launch_bounds__(256) void scan_gcount_kernel(
    int* __restrict__ gcount, const int* __restrict__ bbase, int nblk) {
    __shared__ int s[256];
    int t = threadIdx.x;
    int v = (t < nblk) ? gcount[(size_t)blockIdx.x * nblk + t] : 0;
    s[t] = v;
    __syncthreads();
    for (int off = 1; off < 256; off <<= 1) {
        int add = (t >= off) ? s[t - off] : 0;
        __syncthreads();
        s[t] += add;
        __syncthreads();
    }
    if (t < nblk)
        gcount[(size_t)blockIdx.x * nblk + t] = bbase[blockIdx.x] + s[t] - v;
}

// Pass C: scatter edges into bucket-grouped es_tmp={s,d}. LDS atomics only.
__global__ __launch_bounds__(256) void bucket_scatter_kernel(
    const int* __restrict__ s32, const int* __restrict__ d32,
    const int* __restrict__ gofs, int2* __restrict__ es_tmp,
    int E, int nblk, int nbuk, int ch) {
    __shared__ int cur[NBUK_MAX];
    for (int i = threadIdx.x; i < nbuk; i += 256)
        cur[i] = gofs[(size_t)i * nblk + blockIdx.x];
    __syncthreads();
    int base = blockIdx.x * ch;
    int lim = min(base + ch, E);
    for (int e = base + threadIdx.x; e < lim; e += 256) {
        int s = s32[e], d = d32[e];
        int p = atomicAdd(&cur[d >> 8], 1);
        es_tmp[p] = make_int2(s, d);
    }
}

// Pass D: per-bucket node-level counting sort -> es, row_ofs, dinv.
__global__ __launch_bounds__(256) void bucket_sort_kernel(
    const int2* __restrict__ es_tmp, const int* __restrict__ bbase,
    int* __restrict__ es, int* __restrict__ row_ofs, float* __restrict__ dinv,
    int N) {
    __shared__ int hist[256];
    __shared__ int lofs[256];
    int b = blockIdx.x;
    int t = threadIdx.x;
    int beg = bbase[b], end = bbase[b + 1];
    hist[t] = 0;
    __syncthreads();
    for (int j = beg + t; j < end; j += 256)
        atomicAdd(&hist[es_tmp[j].y & 255], 1);
    __syncthreads();
    int v = hist[t];
    lofs[t] = v;
    __syncthreads();
    for (int off = 1; off < 256; off <<= 1) {
        int add = (t >= off) ? lofs[t - off] : 0;
        __syncthreads();
        lofs[t] += add;
        __syncthreads();
    }
    int excl = lofs[t] - v;
    int node = (b << 8) + t;
    if (node <= N) row_ofs[node] = beg + excl;
    if (node < N) dinv[node] = rsqrtf((float)v + 1.0f);
    __syncthreads();
    lofs[t] = beg + excl;  // running cursor
    __syncthreads();
    for (int j = beg + t; j < end; j += 256) {
        int2 ed = es_tmp[j];
        int p = atomicAdd(&lofs[ed.y & 255], 1);
        es[p] = ed.x;
    }
}

// ---------------------------------------------------------------------------
// F=64 bf16 gather over PRE-SCALED rows h'[n]=h[n]*dinv[n]:
//   out[n] = (sum_e h'[src_e] + h'[n]) * dinv[n]
// wave/node; 4 groups x 16 lanes x uint2; 4-deep = 16 edge rows in flight.
// Inner loop: 1 load + unpack + 4 masked FMA. No per-edge norm work.
// ---------------------------------------------------------------------------
__global__ __launch_bounds__(256) void gather64_bf16_kernel(
    const unsigned short* __restrict__ hb, const int* __restrict__ es,
    const int* __restrict__ row_ofs, const float* __restrict__ dinv,
    float* __restrict__ agg, int N) {
    int node = (blockIdx.x * blockDim.x + threadIdx.x) >> 6;
    if (node >= N) return;
    int lane = threadIdx.x & 63;
    int g = lane >> 4, l = lane & 15;
    int beg = row_ofs[node], end = row_ofs[node + 1];
    float dd = dinv[node];

    float4 acc = make_float4(0.f, 0.f, 0.f, 0.f);
    for (int base = beg; base < end; base += 16) {
        int s[4]; float m[4]; uint2 hv[4];
#pragma unroll
        for (int u = 0; u < 4; ++u) {
            int j = base + 4 * u + g;
            bool v = j < end;
            m[u] = v ? 1.0f : 0.0f;
            s[u] = es[v ? j : beg];
        }
#pragma unroll
        for (int u = 0; u < 4; ++u)
            hv[u] = *(const uint2*)&hb[(size_t)s[u] * 64 + 4 * l];
#pragma unroll
        for (int u = 0; u < 4; ++u) {
            float4 hh = bf4_to_f4(hv[u]);
            acc.x = fmaf(hh.x, m[u], acc.x); acc.y = fmaf(hh.y, m[u], acc.y);
            acc.z = fmaf(hh.z, m[u], acc.z); acc.w = fmaf(hh.w, m[u], acc.w);
        }
    }
#pragma unroll
    for (int mask = 16; mask <= 32; mask <<= 1) {
        acc.x += __shfl_xor(acc.x, mask);
        acc.y += __shfl_xor(acc.y, mask);
        acc.z += __shfl_xor(acc.z, mask);
        acc.w += __shfl_xor(acc.w, mask);
    }
    if (g == 0) {
        float4 sv = bf4_to_f4(*(const uint2*)&hb[(size_t)node * 64 + 4 * l]);
        acc.x = (acc.x + sv.x) * dd; acc.y = (acc.y + sv.y) * dd;
        acc.z = (acc.z + sv.z) * dd; acc.w = (acc.w + sv.w) * dd;
        *(float4*)&agg[(size_t)node * 64 + 4 * l] = acc;
    }
}

// ---------------------------------------------------------------------------
// F=40 bf16 gather over PRE-SCALED rows; 6 groups x 10 lanes x uint2;
// 3-deep = 18 edges in flight.
//   r = (sum_e h'[src] + h'[n]) * dd (+ b)
// OUTLEAKY_BF16: leaky, re-scale by dd, store bf16 (feeds next gather).
// Else: store fp32 (feeds l3head).
// ---------------------------------------------------------------------------
template <bool BIAS, bool OUTLEAKY_BF16>
__global__ __launch_bounds__(256) void gather40_bf16_kernel(
    const unsigned short* __restrict__ hb, const int* __restrict__ es,
    const int* __restrict__ row_ofs, const float* __restrict__ dinv,
    const float* __restrict__ b, void* __restrict__ aggv, int N) {
    int node = (blockIdx.x * blockDim.x + threadIdx.x) >> 6;
    if (node >= N) return;
    int lane = threadIdx.x & 63;
    int g = lane / 10;
    int l = lane - g * 10;
    bool lv = lane < 60;
    int beg = row_ofs[node], end = row_ofs[node + 1];
    float dd = dinv[node];

    float4 acc = make_float4(0.f, 0.f, 0.f, 0.f);
    for (int base = beg; base < end; base += 18) {
        int s[3]; float m[3]; uint2 hv[3];
#pragma unroll
        for (int u = 0; u < 3; ++u) {
            int j = base + 6 * u + g;
            bool v = lv && (j < end);
            m[u] = v ? 1.0f : 0.0f;
            s[u] = es[v ? j : beg];
        }
#pragma unroll
        for (int u = 0; u < 3; ++u)
            hv[u] = *(const uint2*)&hb[(size_t)s[u] * 40 + 4 * l];
#pragma unroll
        for (int u = 0; u < 3; ++u) {
            float4 hh = bf4_to_f4(hv[u]);
            acc.x = fmaf(hh.x, m[u], acc.x); acc.y = fmaf(hh.y, m[u], acc.y);
            acc.z = fmaf(hh.z, m[u], acc.z); acc.w = fmaf(hh.w, m[u], acc.w);
        }
    }
    float4 r = acc;
#pragma unroll
    for (int o = 10; o <= 50; o += 10) {
        r.x += __shfl(acc.x, lane + o);
        r.y += __shfl(acc.y, lane + o);
        r.z += __shfl(acc.z, lane + o);
        r.w += __shfl(acc.w, lane + o);
    }
    if (lane < 10) {
        float4 sv = bf4_to_f4(*(const uint2*)&hb[(size_t)node * 40 + 4 * l]);
        r.x = (r.x + sv.x) * dd; r.y = (r.y + sv.y) * dd;
        r.z = (r.z + sv.z) * dd; r.w = (r.w + sv.w) * dd;
        if (BIAS) {
            float4 bv = *(const float4*)&b[4 * l];
            r.x += bv.x; r.y += bv.y; r.z += bv.z; r.w += bv.w;
        }
        if (OUTLEAKY_BF16) {
            r.x = LEAKY(r.x); r.y = LEAKY(r.y); r.z = LEAKY(r.z); r.w = LEAKY(r.w);
            ushort4 o;
            o.x = f2bf(r.x * dd); o.y = f2bf(r.y * dd);
            o.z = f2bf(r.z * dd); o.w = f2bf(r.w * dd);
            *(ushort4*)&((unsigned short*)aggv)[(size_t)node * 40 + 4 * l] = o;
        } else {
            *(float4*)&((float*)aggv)[(size_t)node * 40 + 4 * l] = r;
        }
    }
}

// ---------------------------------------------------------------------------
// Register-tiled GEMM: h[n,m] = sum_k act(x[n,k]) * W[k,m] (+ b[m]).
// OUT_BF16 (requires M%4==0): pack 4 bf16 per store; SCALE: pre-multiply the
// stored row by dinv[n] (produces h' for the following gather).
// ---------------------------------------------------------------------------
template <int K, int M, bool ACT, bool BIAS, bool OUT_BF16, bool SCALE>
__global__ __launch_bounds__(256) void gemm_tiled(const float* __restrict__ x,
                                                  const float* __restrict__ W,
                                                  const float* __restrict__ b,
                                                  const float* __restrict__ dinv,
                                                  void* __restrict__ hv, int N) {
    constexpr int MT = 4;
    constexpr int MC = (M + MT - 1) / MT;
    constexpr int MP = MC * MT;
    constexpr int NR = 256 / MC;
    constexpr int NT = 4;
    constexpr int BN = NR * NT;
    static_assert(K % 4 == 0, "K multiple of 4");
    static_assert(!OUT_BF16 || M % 4 == 0, "bf16 out needs M%4==0");

    __shared__ float ws[K * MP];
    for (int i = threadIdx.x; i < K * MP; i += 256) {
        int k = i / MP, m = i - k * MP;
        ws[i] = (m < M) ? W[k * M + m] : 0.0f;
    }
    __syncthreads();

    const int c = threadIdx.x % MC;
    const int r = threadIdx.x / MC;
    if (r >= NR) return;
    const int n0 = blockIdx.x * BN + r * NT;

    float acc[NT][MT];
#pragma unroll
    for (int i = 0; i < NT; ++i)
#pragma unroll
        for (int j = 0; j < MT; ++j) {
            int m = c * MT + j;
            acc[i][j] = (BIAS && m < M) ? b[m] : 0.0f;
        }

    for (int k = 0; k < K; k += 4) {
        float4 wv[4];
#pragma unroll
        for (int kk = 0; kk < 4; ++kk)
            wv[kk] = *(const float4*)&ws[(k + kk) * MP + c * MT];
#pragma unroll
        for (int i = 0; i < NT; ++i) {
            int n = n0 + i;
            if (n < N) {
                float4 xv = *(const float4*)&x[(long long)n * K + k];
                if (ACT) {
                    xv.x = LEAKY(xv.x); xv.y = LEAKY(xv.y);
                    xv.z = LEAKY(xv.z); xv.w = LEAKY(xv.w);
                }
                const float xs[4] = {xv.x, xv.y, xv.z, xv.w};
#pragma unroll
                for (int kk = 0; kk < 4; ++kk) {
                    const float* wp = (const float*)&wv[kk];
#pragma unroll
                    for (int j = 0; j < MT; ++j)
                        acc[i][j] = fmaf(xs[kk], wp[j], acc[i][j]);
                }
            }
        }
    }

#pragma unroll
    for (int i = 0; i < NT; ++i) {
        int n = n0 + i;
        if (n >= N) continue;
        float sc = SCALE ? dinv[n] : 1.0f;
        int m = c * MT;
        if (OUT_BF16) {
            ushort4 o;
            o.x = f2bf(acc[i][0] * sc); o.y = f2bf(acc[i][1] * sc);
            o.z = f2bf(acc[i][2] * sc); o.w = f2bf(acc[i][3] * sc);
            *(ushort4*)&((unsigned short*)hv)[(long long)n * M + m] = o;
        } else {
            float* hp = (float*)hv + (long long)n * M + m;
            if (M % 4 == 0) {
                *(float4*)hp = make_float4(acc[i][0] * sc, acc[i][1] * sc,
                                           acc[i][2] * sc, acc[i][3] * sc);
            } else if (m + MT <= M) {
                *(float2*)hp = make_float2(acc[i][0] * sc, acc[i][1] * sc);
                *(float2*)(hp + 2) = make_float2(acc[i][2] * sc, acc[i][3] * sc);
            } else {
#pragma unroll
                for (int j = 0; j < MT; ++j)
                    if (m + j < M) hp[j] = acc[i][j] * sc;
            }
        }
    }
}

// ---------------------------------------------------------------------------
// Fused L3-GEMM (40->50, +b3) + leaky + head (50x10, +bl) + log_softmax.
// ---------------------------------------------------------------------------
__global__ __launch_bounds__(256) void l3head_kernel(
    const float* __restrict__ P, const float* __restrict__ W3,
    const float* __restrict__ b3, const float* __restrict__ Wl,
    const float* __restrict__ bl, float* __restrict__ out, int N) {
    __shared__ float w3s[40 * 50];
    __shared__ float b3s[50];
    __shared__ float wls[50 * 10];
    __shared__ float bls[10];
    for (int i = threadIdx.x; i < 2000; i += 256) w3s[i] = W3[i];
    for (int i = threadIdx.x; i < 500; i += 256) wls[i] = Wl[i];
    if (threadIdx.x < 50) b3s[threadIdx.x] = b3[threadIdx.x];
    if (threadIdx.x < 10) bls[threadIdx.x] = bl[threadIdx.x];
    __syncthreads();
    int n = blockIdx.x * blockDim.x + threadIdx.x;
    if (n >= N) return;

    float p[40];
    const float4* pr = (const float4*)(P + (size_t)n * 40);
#pragma unroll
    for (int q = 0; q < 10; ++q) {
        float4 t = pr[q];
        p[4 * q + 0] = t.x; p[4 * q + 1] = t.y; p[4 * q + 2] = t.z; p[4 * q + 3] = t.w;
    }
    float logits[10];
#pragma unroll
    for (int j = 0; j < 10; ++j) logits[j] = bls[j];
    for (int m = 0; m < 50; ++m) {
        float acc = b3s[m];
#pragma unroll
        for (int k = 0; k < 40; ++k) acc = fmaf(p[k], w3s[k * 50 + m], acc);
        float v = LEAKY(acc);
#pragma unroll
        for (int j = 0; j < 10; ++j) logits[j] = fmaf(v, wls[m * 10 + j], logits[j]);
    }
    float mx = logits[0];
#pragma unroll
    for (int j = 1; j < 10; ++j) mx = fmaxf(mx, logits[j]);
    float s = 0.0f;
#pragma unroll
    for (int j = 0; j < 10; ++j) s += __expf(logits[j] - mx);
    float lse = __logf(s) + mx;
    float* op = out + (size_t)n * 10;
#pragma unroll
    for (int j = 0; j < 10; ++j) op[j] = logits[j] - lse;
}

extern "C" void kernel_launch(void* const* d_in, const int* in_sizes, int n_in,
                              void* d_out, int out_size, void* d_ws, size_t ws_size,
                              hipStream_t stream) {
    const float* x  = (const float*)d_in[0];
    const unsigned* ei = (const unsigned*)d_in[1];
    const float* W1 = (const float*)d_in[2];
    const float* b1 = (const float*)d_in[3];
    const float* W2 = (const float*)d_in[4];
    const float* b2 = (const float*)d_in[5];
    const float* W3 = (const float*)d_in[6];
    const float* b3 = (const float*)d_in[7];
    const float* Wl = (const float*)d_in[8];
    const float* bl = (const float*)d_in[9];
    float* out = (float*)d_out;

    const int N = in_sizes[0] / 64;
    const int E = in_sizes[1] / 2;

    // counting-sort geometry
    int ch = 4096;
    int nblk = (E + ch - 1) / ch;
    if (nblk > 256) { ch = (E + 255) / 256; nblk = (E + ch - 1) / ch; }
    const int nbuk = (N + 255) >> 8;  // <= 512 (N <= 131072)

    char* wp = (char*)d_ws;
    auto alloc = [&](size_t bytes) {
        char* p = wp;
        wp += (bytes + 255) & ~(size_t)255;
        return p;
    };
    int*   es      = (int*)alloc((size_t)E * 4);
    float* dinv    = (float*)alloc((size_t)N * 4);
    int*   row_ofs = (int*)alloc((size_t)(N + 1) * 4);
    int*   gcount  = (int*)alloc((size_t)nbuk * nblk * 4);
    int*   btot    = (int*)alloc((size_t)NBUK_MAX * 4);
    int*   bbase   = (int*)alloc((size_t)(NBUK_MAX + 1) * 4);
    float* P       = (float*)alloc((size_t)N * 64 * 4);  // 25.6 MB region
    float* A       = (float*)alloc((size_t)N * 80 * 4);  // 32 MB region

    // aliases (all uses strictly sequential; host regions dead at alias use):
    int*   s32    = (int*)P;                    // passes A-C; P written by gather64 later
    int*   d32    = (int*)P + E;
    int2*  es_tmp = (int2*)A;                   // passes C-D (E*8 bytes)
    // xb: bf16 x'=x*dinv copy, N*64*2, inside A past es_tmp (cvt runs after D)
    size_t xb_off = (((size_t)E * 8) + 255) & ~(size_t)255;
    unsigned short* xb = (unsigned short*)((char*)A + xb_off);  // dead once gemm1 writes A
    // Pb: bf16 gemm2 output (N*40*2) at tail of P (beyond fp32 N*40*4 output)
    size_t pb_off = (((size_t)N * 64 * 4) - ((size_t)N * 40 * 2)) & ~(size_t)255;
    unsigned short* Pb = (unsigned short*)((char*)P + pb_off);
    // Ab: bf16 leaky(conv2-out)*dinv (N*40*2) at tail of A
    size_t ab_off = (((size_t)N * 80 * 4) - ((size_t)N * 40 * 2)) & ~(size_t)255;
    unsigned short* Ab = (unsigned short*)((char*)A + ab_off);

    const int B = 256;

    // ---- CSR build: atomic-free two-level counting sort ----
    bucket_count_kernel<<<nblk, B, 0, stream>>>(ei, s32, d32, gcount, E, nblk, nbuk, ch);
    bucket_total_kernel<<<nbuk, B, 0, stream>>>(gcount, btot, nblk);
    scan_btot_kernel<<<1, 512, 0, stream>>>(btot, bbase, row_ofs, nbuk, N, E);
    scan_gcount_kernel<<<nbuk, B, 0, stream>>>(gcount, bbase, nblk);
    bucket_scatter_kernel<<<nblk, B, 0, stream>>>(s32, d32, gcount, es_tmp, E, nblk, nbuk, ch);
    bucket_sort_kernel<<<nbuk, B, 0, stream>>>(es_tmp, bbase, es, row_ofs, dinv, N);

    // xb = bf16(x * dinv) — needs dinv, hence after the CSR build
    cvt_scale_kernel<<<(N * 16 + B - 1) / B, B, 0, stream>>>(x, dinv, (ushort4*)xb, N);

    const int gblocks = (N * 64 + B - 1) / B;  // one wave per node

    auto gb = [&](int M) {
        int MC = (M + 3) / 4;
        int BN = (256 / MC) * 4;
        return (N + BN - 1) / BN;
    };

    // L1: agg(xb) (pre-scaled bf16 gather), then GEMM(+b1) fp32
    gather64_bf16_kernel<<<gblocks, B, 0, stream>>>(xb, es, row_ofs, dinv, P, N);
    gemm_tiled<64, 80, false, true, false, false><<<gb(80), B, 0, stream>>>(P, W1, b1, nullptr, A, N);

    // L2: GEMM first: Pb = bf16((leaky(A)@W2) * dinv); gather(+b2) -> leaky*dinv -> Ab
    gemm_tiled<80, 40, true, false, true, true><<<gb(40), B, 0, stream>>>(A, W2, nullptr, dinv, Pb, N);
    gather40_bf16_kernel<true, true><<<gblocks, B, 0, stream>>>(Pb, es, row_ofs, dinv, b2, Ab, N);

    // L3: agg(Ab) -> P fp32, then fused GEMM+head
    gather40_bf16_kernel<false, false><<<gblocks, B, 0, stream>>>(Ab, es, row_ofs, dinv, nullptr, P, N);
    l3head_kernel<<<(N + B - 1) / B, B, 0, stream>>>(P, W3, b3, Wl, bl, out, N);
}